// Round 3
// baseline (1973.917 us; speedup 1.0000x reference)
//
#include <hip/hip_runtime.h>
#include <hip/hip_bf16.h>
#include <float.h>

#define DD 128
#define NEG_SLOPE 0.2f

typedef __attribute__((ext_vector_type(8))) short bf16x8;
typedef __attribute__((ext_vector_type(4))) float f32x4;

__device__ __forceinline__ float lrelu(float v) {
    return fmaxf(v, 0.0f) + NEG_SLOPE * fminf(v, 0.0f);
}

__device__ __forceinline__ unsigned short f2bf(float f) {
    unsigned u = __float_as_uint(f);
    u += 0x7fff + ((u >> 16) & 1);   // round-to-nearest-even
    return (unsigned short)(u >> 16);
}
__device__ __forceinline__ float bf2f(unsigned short h) {
    return __uint_as_float(((unsigned)h) << 16);
}

// ---------------- preprocessing ----------------

__global__ void k_hist(const int* __restrict__ dst, int E, int* __restrict__ cnt) {
    int i = blockIdx.x * blockDim.x + threadIdx.x;
    if (i < E) atomicAdd(&cnt[dst[i]], 1);
}

__global__ __launch_bounds__(1024) void k_scan(const int* __restrict__ cnt,
                                               int* __restrict__ row_ptr, int N) {
    __shared__ int sums[1024];
    int tid = threadIdx.x;
    int total = N + 1;
    int chunk = (total + 1023) / 1024;
    int lo = tid * chunk;
    int hi = min(lo + chunk, total);
    int s = 0;
    for (int i = lo; i < hi; ++i) s += (i < N) ? (cnt[i] + 1) : 0;
    sums[tid] = s;
    __syncthreads();
    for (int off = 1; off < 1024; off <<= 1) {
        int t = (tid >= off) ? sums[tid - off] : 0;
        __syncthreads();
        sums[tid] += t;
        __syncthreads();
    }
    int run = sums[tid] - s;
    for (int i = lo; i < hi; ++i) {
        row_ptr[i] = run;
        run += (i < N) ? (cnt[i] + 1) : 0;
    }
}

__global__ void k_scatter(const int* __restrict__ dst, int E, int N,
                          const int* __restrict__ row_ptr, int* __restrict__ fill,
                          const int* __restrict__ cnt, int* __restrict__ eids) {
    int i = blockIdx.x * blockDim.x + threadIdx.x;
    int tot = E + N;
    if (i >= tot) return;
    if (i < E) {
        int d = dst[i];
        int p = atomicAdd(&fill[d], 1);
        eids[row_ptr[d] + p] = i;
    } else {
        int n = i - E;
        eids[row_ptr[n] + cnt[n]] = E + n;
    }
}

// canonicalize row order (atomic scatter order varies per launch)
__global__ void k_sort_rows(const int* __restrict__ row_ptr, int* __restrict__ eids, int N) {
    int n = blockIdx.x * blockDim.x + threadIdx.x;
    if (n >= N) return;
    int s = row_ptr[n], e = row_ptr[n + 1];
    for (int i = s + 1; i < e; ++i) {
        int v = eids[i];
        int j = i - 1;
        while (j >= s && eids[j] > v) { eids[j + 1] = eids[j]; --j; }
        eids[j + 1] = v;
    }
}

__global__ __launch_bounds__(128) void k_loop_attr(const float* __restrict__ ea,
                                                   const int* __restrict__ row_ptr,
                                                   const int* __restrict__ cnt,
                                                   const int* __restrict__ eids,
                                                   float* __restrict__ loop_attr, int N) {
    int n = blockIdx.x;
    int d = threadIdx.x;
    int s = row_ptr[n];
    int c = cnt[n];
    float acc = 0.f;
    for (int p = 0; p < c; ++p) {
        int e = eids[s + p];
        acc += ea[(size_t)e * DD + d];
    }
    loop_attr[(size_t)n * DD + d] = acc / fmaxf((float)c, 1.0f);
}

// prepack We (per layer) into MFMA A-fragment order, bf16 hi/lo.
// WA[l][h][ks][g][j][i] = bf16_h( We[l][ks*32+g*8+i][j] ),  j=0..127, i=0..7
__global__ void k_prepack(const float* __restrict__ We, unsigned short* __restrict__ WA, int L) {
    int idx = blockIdx.x * blockDim.x + threadIdx.x;
    int total = L * DD * DD;
    if (idx >= total) return;
    int l = idx >> 14;
    int rem = idx & 16383;
    int k = rem >> 7;
    int j = rem & 127;
    float w = We[(size_t)l * 16384 + (size_t)k * DD + j];
    unsigned short h = f2bf(w);
    unsigned short lo = f2bf(w - bf2f(h));
    int ks = k >> 5, g = (k >> 3) & 3, i = k & 7;
    size_t off = ((size_t)(ks * 4 + g) * DD + j) * 8 + i;   // within half
    unsigned short* base = WA + (size_t)l * 32768;
    base[off] = h;
    base[16384 + off] = lo;
}

// ---------------- per-layer kernels ----------------

// Y[N,128] = X[N,128] @ W[128,128] + b[128]
__global__ __launch_bounds__(256) void k_gemm_nn(const float* __restrict__ X,
                                                 const float* __restrict__ W,
                                                 const float* __restrict__ b,
                                                 float* __restrict__ Y, int N) {
    __shared__ float As[128][9];
    __shared__ float Bs[8][128];
    int tid = threadIdx.x;
    int tr = tid >> 4, tc = tid & 15;
    int r0 = blockIdx.x * 128;
    float acc[8][8] = {};
    for (int k0 = 0; k0 < 128; k0 += 8) {
        {
            int r = tid >> 1, half = tid & 1;
            int gr = r0 + r;
            float4 v = make_float4(0.f, 0.f, 0.f, 0.f);
            if (gr < N) v = *reinterpret_cast<const float4*>(&X[(size_t)gr * DD + k0 + half * 4]);
            As[r][half * 4 + 0] = v.x;
            As[r][half * 4 + 1] = v.y;
            As[r][half * 4 + 2] = v.z;
            As[r][half * 4 + 3] = v.w;
        }
        {
            int kk = tid >> 5, c4 = tid & 31;
            *reinterpret_cast<float4*>(&Bs[kk][c4 * 4]) =
                *reinterpret_cast<const float4*>(&W[(size_t)(k0 + kk) * DD + c4 * 4]);
        }
        __syncthreads();
        #pragma unroll
        for (int kk = 0; kk < 8; ++kk) {
            float a[8], bb[8];
            #pragma unroll
            for (int i = 0; i < 8; ++i) a[i] = As[tr * 8 + i][kk];
            #pragma unroll
            for (int j = 0; j < 8; ++j) bb[j] = Bs[kk][tc * 8 + j];
            #pragma unroll
            for (int i = 0; i < 8; ++i)
                #pragma unroll
                for (int j = 0; j < 8; ++j)
                    acc[i][j] += a[i] * bb[j];
        }
        __syncthreads();
    }
    #pragma unroll
    for (int i = 0; i < 8; ++i) {
        int gr = r0 + tr * 8 + i;
        if (gr >= N) continue;
        #pragma unroll
        for (int j0 = 0; j0 < 8; j0 += 4) {
            int c = tc * 8 + j0;
            float4 o;
            o.x = acc[i][j0 + 0] + b[c + 0];
            o.y = acc[i][j0 + 1] + b[c + 1];
            o.z = acc[i][j0 + 2] + b[c + 2];
            o.w = acc[i][j0 + 3] + b[c + 3];
            *reinterpret_cast<float4*>(&Y[(size_t)gr * DD + c]) = o;
        }
    }
}

// MFMA edge-logits: D[j][e] = sum_k We[k][j]*ea[e][k]  (bf16x2 split, 3 products)
// wave = 64 edges (4 N-frags) x 128 features (8 M-frags); block = 4 waves = 256 edges.
// epilogue: t = D + xl[src] + xr[dst]; logit[e] = sum_j att[j]*lrelu(t[j])
__global__ __launch_bounds__(256, 2) void k_edge_mfma(
    const float* __restrict__ ea, const float* __restrict__ loop_attr,
    const int* __restrict__ srcArr, const int* __restrict__ dstArr,
    const unsigned short* __restrict__ WA, const float* __restrict__ att,
    const float* __restrict__ xl, const float* __restrict__ xr,
    float* __restrict__ logits, int E, int Etot) {

    int tid  = threadIdx.x;
    int lane = tid & 63;
    int wv   = tid >> 6;
    int lc   = lane & 15;   // edge-within-frag (B cols) / feature-within-frag (A rows)
    int g    = lane >> 4;   // k-group

    int e0 = blockIdx.x * 256 + wv * 64;

    // per-(lane,nf) edge rows
    const float* rp[4];
    int   sn[4], dn[4];
    bool  ok[4];
    int   ev[4];
    #pragma unroll
    for (int nf = 0; nf < 4; ++nf) {
        int e = e0 + nf * 16 + lc;
        ev[nf] = e;
        ok[nf] = (e < Etot);
        if (e < E)            { rp[nf] = ea + (size_t)e * DD; sn[nf] = srcArr[e]; dn[nf] = dstArr[e]; }
        else if (e < Etot)    { rp[nf] = loop_attr + (size_t)(e - E) * DD; sn[nf] = e - E; dn[nf] = e - E; }
        else                  { rp[nf] = ea; sn[nf] = 0; dn[nf] = 0; }
    }

    f32x4 acc[8][4];
    #pragma unroll
    for (int m = 0; m < 8; ++m)
        #pragma unroll
        for (int n = 0; n < 4; ++n)
            acc[m][n] = (f32x4){0.f, 0.f, 0.f, 0.f};

    #pragma unroll
    for (int ks = 0; ks < 4; ++ks) {
        // A fragments (We^T): 8 feature-frags x {hi,lo}
        bf16x8 Ah[8], Al[8];
        #pragma unroll
        for (int mf = 0; mf < 8; ++mf) {
            size_t off = ((size_t)(ks * 4 + g) * DD + (mf * 16 + lc)) * 8;
            Ah[mf] = *reinterpret_cast<const bf16x8*>(WA + off);
            Al[mf] = *reinterpret_cast<const bf16x8*>(WA + 16384 + off);
        }
        int k0 = ks * 32 + g * 8;
        #pragma unroll
        for (int nf = 0; nf < 4; ++nf) {
            float4 v0, v1;
            if (ok[nf]) {
                v0 = *reinterpret_cast<const float4*>(rp[nf] + k0);
                v1 = *reinterpret_cast<const float4*>(rp[nf] + k0 + 4);
            } else {
                v0 = make_float4(0.f, 0.f, 0.f, 0.f);
                v1 = v0;
            }
            float v[8] = {v0.x, v0.y, v0.z, v0.w, v1.x, v1.y, v1.z, v1.w};
            bf16x8 Bh, Bl;
            #pragma unroll
            for (int i = 0; i < 8; ++i) {
                unsigned short h = f2bf(v[i]);
                Bh[i] = (short)h;
                Bl[i] = (short)f2bf(v[i] - bf2f(h));
            }
            #pragma unroll
            for (int mf = 0; mf < 8; ++mf) {
                acc[mf][nf] = __builtin_amdgcn_mfma_f32_16x16x32_bf16(Ah[mf], Bh, acc[mf][nf], 0, 0, 0);
                acc[mf][nf] = __builtin_amdgcn_mfma_f32_16x16x32_bf16(Al[mf], Bh, acc[mf][nf], 0, 0, 0);
                acc[mf][nf] = __builtin_amdgcn_mfma_f32_16x16x32_bf16(Ah[mf], Bl, acc[mf][nf], 0, 0, 0);
            }
        }
    }

    // epilogue: per acc reg r, feature f = mf*16 + g*4 + r; edge = ev[nf]
    float partial[4] = {0.f, 0.f, 0.f, 0.f};
    #pragma unroll
    for (int mf = 0; mf < 8; ++mf) {
        int f0 = mf * 16 + g * 4;
        float4 attv = *reinterpret_cast<const float4*>(att + f0);
        #pragma unroll
        for (int nf = 0; nf < 4; ++nf) {
            float4 xlv = *reinterpret_cast<const float4*>(xl + (size_t)sn[nf] * DD + f0);
            float4 xrv = *reinterpret_cast<const float4*>(xr + (size_t)dn[nf] * DD + f0);
            float t0 = acc[mf][nf][0] + xlv.x + xrv.x;
            float t1 = acc[mf][nf][1] + xlv.y + xrv.y;
            float t2 = acc[mf][nf][2] + xlv.z + xrv.z;
            float t3 = acc[mf][nf][3] + xlv.w + xrv.w;
            partial[nf] += attv.x * lrelu(t0) + attv.y * lrelu(t1)
                         + attv.z * lrelu(t2) + attv.w * lrelu(t3);
        }
    }
    #pragma unroll
    for (int nf = 0; nf < 4; ++nf) {
        float p = partial[nf];
        p += __shfl_xor(p, 16);
        p += __shfl_xor(p, 32);
        if (lane < 16 && ok[nf]) logits[ev[nf]] = p;
    }
}

// per-destination softmax + aggregation over CSR
__global__ __launch_bounds__(128) void k_node_agg(
    const float* __restrict__ logits, const int* __restrict__ row_ptr,
    const int* __restrict__ eids, const int* __restrict__ srcArr,
    const float* __restrict__ xl, const float* __restrict__ bias,
    float* __restrict__ xout, int N, int E) {
    __shared__ float red[128];
    __shared__ float s_alpha[128];
    __shared__ int s_s[128];
    int n = blockIdx.x;
    int t = threadIdx.x;
    int s = row_ptr[n], e = row_ptr[n + 1];
    float mx = -FLT_MAX;
    for (int p = s + t; p < e; p += 128) mx = fmaxf(mx, logits[eids[p]]);
    red[t] = mx; __syncthreads();
    for (int off = 64; off; off >>= 1) {
        if (t < off) red[t] = fmaxf(red[t], red[t + off]);
        __syncthreads();
    }
    mx = red[0]; __syncthreads();
    float sm = 0.f;
    for (int p = s + t; p < e; p += 128) sm += __expf(logits[eids[p]] - mx);
    red[t] = sm; __syncthreads();
    for (int off = 64; off; off >>= 1) {
        if (t < off) red[t] += red[t + off];
        __syncthreads();
    }
    float inv = 1.0f / red[0];
    float acc = 0.f;
    for (int p0 = s; p0 < e; p0 += 128) {
        int m = min(128, e - p0);
        __syncthreads();
        if (t < m) {
            int eid = eids[p0 + t];
            s_alpha[t] = __expf(logits[eid] - mx) * inv;
            s_s[t] = (eid < E) ? srcArr[eid] : (eid - E);
        }
        __syncthreads();
        for (int q = 0; q < m; ++q)
            acc += s_alpha[q] * xl[(size_t)s_s[q] * DD + t];
    }
    xout[(size_t)n * DD + t] = acc + bias[t];
}

// ---------------- final score + top-k ----------------

__global__ __launch_bounds__(256) void k_scores(const float* __restrict__ X,
                                                const float* __restrict__ Wf,
                                                const float* __restrict__ bf,
                                                float* __restrict__ scores, int N) {
    int gid = blockIdx.x * blockDim.x + threadIdx.x;
    int node = gid >> 6;
    int lane = threadIdx.x & 63;
    if (node >= N) return;
    float2 xv = *reinterpret_cast<const float2*>(&X[(size_t)node * DD + lane * 2]);
    float2 wv = *reinterpret_cast<const float2*>(&Wf[lane * 2]);
    float p = xv.x * wv.x + xv.y * wv.y;
    p += __shfl_xor(p, 32);
    p += __shfl_xor(p, 16);
    p += __shfl_xor(p, 8);
    p += __shfl_xor(p, 4);
    p += __shfl_xor(p, 2);
    p += __shfl_xor(p, 1);
    if (lane == 0) scores[node] = p + bf[0];
}

__device__ __forceinline__ bool tk_better(float a, int ai, float b, int bi) {
    return (a > b) || (a == b && ai < bi);
}

__global__ __launch_bounds__(1024) void k_topk(const float* __restrict__ scores, int N,
                                               float* __restrict__ out) {
    __shared__ float lv[1024 * 10];
    __shared__ int li[1024 * 10];
    int t = threadIdx.x;
    float v[10]; int ix[10];
    #pragma unroll
    for (int j = 0; j < 10; ++j) { v[j] = -FLT_MAX; ix[j] = 0x7fffffff; }
    for (int i = t; i < N; i += 1024) {
        float sv = scores[i];
        if (tk_better(sv, i, v[9], ix[9])) {
            v[9] = sv; ix[9] = i;
            #pragma unroll
            for (int j = 9; j > 0; --j) {
                if (tk_better(v[j], ix[j], v[j - 1], ix[j - 1])) {
                    float tv = v[j]; v[j] = v[j - 1]; v[j - 1] = tv;
                    int ti = ix[j]; ix[j] = ix[j - 1]; ix[j - 1] = ti;
                }
            }
        }
    }
    #pragma unroll
    for (int j = 0; j < 10; ++j) { lv[t * 10 + j] = v[j]; li[t * 10 + j] = ix[j]; }
    __syncthreads();
    for (int sh = 512; sh >= 1; sh >>= 1) {
        if (t < sh) {
            float bv[10]; int bi[10];
            #pragma unroll
            for (int j = 0; j < 10; ++j) { bv[j] = lv[(t + sh) * 10 + j]; bi[j] = li[(t + sh) * 10 + j]; }
            float mv[10]; int mi[10];
            int i1 = 0, i2 = 0;
            #pragma unroll
            for (int k = 0; k < 10; ++k) {
                if (tk_better(v[i1], ix[i1], bv[i2], bi[i2])) { mv[k] = v[i1]; mi[k] = ix[i1]; ++i1; }
                else { mv[k] = bv[i2]; mi[k] = bi[i2]; ++i2; }
            }
            #pragma unroll
            for (int j = 0; j < 10; ++j) {
                v[j] = mv[j]; ix[j] = mi[j];
                lv[t * 10 + j] = v[j]; li[t * 10 + j] = ix[j];
            }
        }
        __syncthreads();
    }
    if (t == 0) {
        #pragma unroll
        for (int j = 0; j < 10; ++j) {
            out[j] = v[j];
            out[10 + j] = (float)ix[j];
        }
    }
}

// ---------------- host launch ----------------

static inline size_t alignup(size_t v) { return (v + 255) & ~(size_t)255; }

extern "C" void kernel_launch(void* const* d_in, const int* in_sizes, int n_in,
                              void* d_out, int out_size, void* d_ws, size_t ws_size,
                              hipStream_t stream) {
    const float* x    = (const float*)d_in[0];
    const int*   ei   = (const int*)d_in[1];
    const float* ea   = (const float*)d_in[2];
    const float* Wl   = (const float*)d_in[3];
    const float* bl   = (const float*)d_in[4];
    const float* Wr   = (const float*)d_in[5];
    const float* br   = (const float*)d_in[6];
    const float* We   = (const float*)d_in[7];
    const float* att  = (const float*)d_in[8];
    const float* bias = (const float*)d_in[9];
    const float* Wf   = (const float*)d_in[10];
    const float* bf   = (const float*)d_in[11];

    int N = in_sizes[0] / DD;
    int E = in_sizes[1] / 2;
    int L = in_sizes[3] / (DD * DD);
    int Etot = E + N;
    const int* src = ei;
    const int* dst = ei + E;

    size_t off = 0;
    char* wsb = (char*)d_ws;
    auto carve = [&](size_t bytes) -> void* { void* p = wsb + off; off += alignup(bytes); return p; };
    unsigned short* WA = (unsigned short*)carve((size_t)L * 32768 * 2);
    int*   cnt       = (int*)carve((size_t)N * 4);
    int*   fill      = (int*)carve((size_t)N * 4);
    int*   row_ptr   = (int*)carve((size_t)(N + 1) * 4);
    int*   eids      = (int*)carve((size_t)Etot * 4);
    float* logits    = (float*)carve((size_t)Etot * 4);
    float* loop_attr = (float*)carve((size_t)N * DD * 4);
    float* xl        = (float*)carve((size_t)N * DD * 4);
    float* xr        = (float*)carve((size_t)N * DD * 4);
    float* xa        = (float*)carve((size_t)N * DD * 4);
    float* xb        = (float*)carve((size_t)N * DD * 4);
    float* scoresBuf = (float*)carve((size_t)N * 4);
    (void)ws_size; (void)n_in; (void)out_size;

    hipMemsetAsync(cnt, 0, (size_t)N * 4, stream);
    hipMemsetAsync(fill, 0, (size_t)N * 4, stream);

    k_prepack<<<(L * DD * DD + 255) / 256, 256, 0, stream>>>(We, WA, L);
    k_hist<<<(E + 255) / 256, 256, 0, stream>>>(dst, E, cnt);
    k_scan<<<1, 1024, 0, stream>>>(cnt, row_ptr, N);
    k_scatter<<<(Etot + 255) / 256, 256, 0, stream>>>(dst, E, N, row_ptr, fill, cnt, eids);
    k_sort_rows<<<(N + 255) / 256, 256, 0, stream>>>(row_ptr, eids, N);
    k_loop_attr<<<N, 128, 0, stream>>>(ea, row_ptr, cnt, eids, loop_attr, N);

    const float* xin = x;
    float* xout = xa;
    int gemmBlocks = (N + 127) / 128;
    int edgeBlocks = (Etot + 255) / 256;
    for (int l = 0; l < L; ++l) {
        k_gemm_nn<<<gemmBlocks, 256, 0, stream>>>(xin, Wl + (size_t)l * DD * DD, bl + (size_t)l * DD, xl, N);
        k_gemm_nn<<<gemmBlocks, 256, 0, stream>>>(xin, Wr + (size_t)l * DD * DD, br + (size_t)l * DD, xr, N);
        k_edge_mfma<<<edgeBlocks, 256, 0, stream>>>(ea, loop_attr, src, dst,
                                                    WA + (size_t)l * 32768, att + (size_t)l * DD,
                                                    xl, xr, logits, E, Etot);
        k_node_agg<<<N, 128, 0, stream>>>(logits, row_ptr, eids, src, xl, bias + (size_t)l * DD, xout, N, E);
        xin = xout;
        xout = (xout == xa) ? xb : xa;
    }
    k_scores<<<(N + 3) / 4, 256, 0, stream>>>(xin, Wf, bf, scoresBuf, N);
    k_topk<<<1, 1024, 0, stream>>>(scoresBuf, N, (float*)d_out);
}

// Round 4
// 1507.025 us; speedup vs baseline: 1.3098x; 1.3098x over previous
//
#include <hip/hip_runtime.h>
#include <hip/hip_bf16.h>
#include <float.h>

#define DD 128
#define NEG_SLOPE 0.2f

typedef __attribute__((ext_vector_type(8))) short bf16x8;
typedef __attribute__((ext_vector_type(4))) float f32x4;

__device__ __forceinline__ float lrelu(float v) {
    return fmaxf(v, 0.0f) + NEG_SLOPE * fminf(v, 0.0f);
}

__device__ __forceinline__ unsigned short f2bf(float f) {
    unsigned u = __float_as_uint(f);
    u += 0x7fff + ((u >> 16) & 1);   // round-to-nearest-even
    return (unsigned short)(u >> 16);
}
__device__ __forceinline__ float bf2f(unsigned short h) {
    return __uint_as_float(((unsigned)h) << 16);
}

// ---------------- preprocessing ----------------

__global__ void k_hist(const int* __restrict__ dst, int E, int* __restrict__ cnt) {
    int i = blockIdx.x * blockDim.x + threadIdx.x;
    if (i < E) atomicAdd(&cnt[dst[i]], 1);
}

__global__ __launch_bounds__(1024) void k_scan(const int* __restrict__ cnt,
                                               int* __restrict__ row_ptr, int N) {
    __shared__ int sums[1024];
    int tid = threadIdx.x;
    int total = N + 1;
    int chunk = (total + 1023) / 1024;
    int lo = tid * chunk;
    int hi = min(lo + chunk, total);
    int s = 0;
    for (int i = lo; i < hi; ++i) s += (i < N) ? (cnt[i] + 1) : 0;
    sums[tid] = s;
    __syncthreads();
    for (int off = 1; off < 1024; off <<= 1) {
        int t = (tid >= off) ? sums[tid - off] : 0;
        __syncthreads();
        sums[tid] += t;
        __syncthreads();
    }
    int run = sums[tid] - s;
    for (int i = lo; i < hi; ++i) {
        row_ptr[i] = run;
        run += (i < N) ? (cnt[i] + 1) : 0;
    }
}

__global__ void k_scatter(const int* __restrict__ dst, int E, int N,
                          const int* __restrict__ row_ptr, int* __restrict__ fill,
                          const int* __restrict__ cnt, int* __restrict__ eids) {
    int i = blockIdx.x * blockDim.x + threadIdx.x;
    int tot = E + N;
    if (i >= tot) return;
    if (i < E) {
        int d = dst[i];
        int p = atomicAdd(&fill[d], 1);
        eids[row_ptr[d] + p] = i;
    } else {
        int n = i - E;
        eids[row_ptr[n] + cnt[n]] = E + n;
    }
}

// canonicalize row order (atomic scatter order varies per launch)
__global__ void k_sort_rows(const int* __restrict__ row_ptr, int* __restrict__ eids, int N) {
    int n = blockIdx.x * blockDim.x + threadIdx.x;
    if (n >= N) return;
    int s = row_ptr[n], e = row_ptr[n + 1];
    for (int i = s + 1; i < e; ++i) {
        int v = eids[i];
        int j = i - 1;
        while (j >= s && eids[j] > v) { eids[j + 1] = eids[j]; --j; }
        eids[j + 1] = v;
    }
}

__global__ __launch_bounds__(128) void k_loop_attr(const float* __restrict__ ea,
                                                   const int* __restrict__ row_ptr,
                                                   const int* __restrict__ cnt,
                                                   const int* __restrict__ eids,
                                                   float* __restrict__ loop_attr, int N) {
    int n = blockIdx.x;
    int d = threadIdx.x;
    int s = row_ptr[n];
    int c = cnt[n];
    float acc = 0.f;
    for (int p = 0; p < c; ++p) {
        int e = eids[s + p];
        acc += ea[(size_t)e * DD + d];
    }
    loop_attr[(size_t)n * DD + d] = acc / fmaxf((float)c, 1.0f);
}

// prepack We (per layer) into MFMA A-fragment order, bf16 hi/lo.
// WA[l][h][ks][g][j][i] = bf16_h( We[l][ks*32+g*8+i][j] ),  j=0..127, i=0..7
__global__ void k_prepack(const float* __restrict__ We, unsigned short* __restrict__ WA, int L) {
    int idx = blockIdx.x * blockDim.x + threadIdx.x;
    int total = L * DD * DD;
    if (idx >= total) return;
    int l = idx >> 14;
    int rem = idx & 16383;
    int k = rem >> 7;
    int j = rem & 127;
    float w = We[(size_t)l * 16384 + (size_t)k * DD + j];
    unsigned short h = f2bf(w);
    unsigned short lo = f2bf(w - bf2f(h));
    int ks = k >> 5, g = (k >> 3) & 3, i = k & 7;
    size_t off = ((size_t)(ks * 4 + g) * DD + j) * 8 + i;   // within half
    unsigned short* base = WA + (size_t)l * 32768;
    base[off] = h;
    base[16384 + off] = lo;
}

// ---------------- per-layer kernels ----------------

// Y[N,128] = X[N,128] @ W[128,128] + b[128]
__global__ __launch_bounds__(256) void k_gemm_nn(const float* __restrict__ X,
                                                 const float* __restrict__ W,
                                                 const float* __restrict__ b,
                                                 float* __restrict__ Y, int N) {
    __shared__ float As[128][9];
    __shared__ float Bs[8][128];
    int tid = threadIdx.x;
    int tr = tid >> 4, tc = tid & 15;
    int r0 = blockIdx.x * 128;
    float acc[8][8] = {};
    for (int k0 = 0; k0 < 128; k0 += 8) {
        {
            int r = tid >> 1, half = tid & 1;
            int gr = r0 + r;
            float4 v = make_float4(0.f, 0.f, 0.f, 0.f);
            if (gr < N) v = *reinterpret_cast<const float4*>(&X[(size_t)gr * DD + k0 + half * 4]);
            As[r][half * 4 + 0] = v.x;
            As[r][half * 4 + 1] = v.y;
            As[r][half * 4 + 2] = v.z;
            As[r][half * 4 + 3] = v.w;
        }
        {
            int kk = tid >> 5, c4 = tid & 31;
            *reinterpret_cast<float4*>(&Bs[kk][c4 * 4]) =
                *reinterpret_cast<const float4*>(&W[(size_t)(k0 + kk) * DD + c4 * 4]);
        }
        __syncthreads();
        #pragma unroll
        for (int kk = 0; kk < 8; ++kk) {
            float a[8], bb[8];
            #pragma unroll
            for (int i = 0; i < 8; ++i) a[i] = As[tr * 8 + i][kk];
            #pragma unroll
            for (int j = 0; j < 8; ++j) bb[j] = Bs[kk][tc * 8 + j];
            #pragma unroll
            for (int i = 0; i < 8; ++i)
                #pragma unroll
                for (int j = 0; j < 8; ++j)
                    acc[i][j] += a[i] * bb[j];
        }
        __syncthreads();
    }
    #pragma unroll
    for (int i = 0; i < 8; ++i) {
        int gr = r0 + tr * 8 + i;
        if (gr >= N) continue;
        #pragma unroll
        for (int j0 = 0; j0 < 8; j0 += 4) {
            int c = tc * 8 + j0;
            float4 o;
            o.x = acc[i][j0 + 0] + b[c + 0];
            o.y = acc[i][j0 + 1] + b[c + 1];
            o.z = acc[i][j0 + 2] + b[c + 2];
            o.w = acc[i][j0 + 3] + b[c + 3];
            *reinterpret_cast<float4*>(&Y[(size_t)gr * DD + c]) = o;
        }
    }
}

// MFMA edge-logits: D[j][e] = sum_k We[k][j]*ea[e][k]  (bf16x2 split, 3 products)
// wave = 32 edges (2 N-frags) x 128 features (8 M-frags); block = 4 waves = 128 edges.
// Register budget kept small (acc[8][2]=64, transient A) to avoid the round-3 spills.
__global__ __launch_bounds__(256, 2) void k_edge_mfma(
    const float* __restrict__ ea, const float* __restrict__ loop_attr,
    const int* __restrict__ srcArr, const int* __restrict__ dstArr,
    const unsigned short* __restrict__ WA, const float* __restrict__ att,
    const float* __restrict__ xl, const float* __restrict__ xr,
    float* __restrict__ logits, int E, int Etot) {

    int tid  = threadIdx.x;
    int lane = tid & 63;
    int wv   = tid >> 6;
    int lc   = lane & 15;   // edge-within-frag (B cols) / feature-within-frag (A rows)
    int g    = lane >> 4;   // k-group

    int e0 = blockIdx.x * 128 + wv * 32;

    const float* rp[2];
    int   sn[2], dn[2], ev[2];
    bool  ok[2];
    #pragma unroll
    for (int nf = 0; nf < 2; ++nf) {
        int e = e0 + nf * 16 + lc;
        ev[nf] = e;
        ok[nf] = (e < Etot);
        if (e < E)            { rp[nf] = ea + (size_t)e * DD; sn[nf] = srcArr[e]; dn[nf] = dstArr[e]; }
        else if (e < Etot)    { rp[nf] = loop_attr + (size_t)(e - E) * DD; sn[nf] = e - E; dn[nf] = e - E; }
        else                  { rp[nf] = ea; sn[nf] = 0; dn[nf] = 0; }
    }

    f32x4 acc[8][2];
    #pragma unroll
    for (int m = 0; m < 8; ++m)
        #pragma unroll
        for (int n = 0; n < 2; ++n)
            acc[m][n] = (f32x4){0.f, 0.f, 0.f, 0.f};

    #pragma unroll
    for (int ks = 0; ks < 4; ++ks) {
        int k0 = ks * 32 + g * 8;
        // B fragments: 2 edge rows, convert f32 -> bf16 hi/lo
        bf16x8 Bh[2], Bl[2];
        #pragma unroll
        for (int nf = 0; nf < 2; ++nf) {
            float4 v0, v1;
            if (ok[nf]) {
                v0 = *reinterpret_cast<const float4*>(rp[nf] + k0);
                v1 = *reinterpret_cast<const float4*>(rp[nf] + k0 + 4);
            } else {
                v0 = make_float4(0.f, 0.f, 0.f, 0.f);
                v1 = v0;
            }
            float v[8] = {v0.x, v0.y, v0.z, v0.w, v1.x, v1.y, v1.z, v1.w};
            #pragma unroll
            for (int i = 0; i < 8; ++i) {
                unsigned short h = f2bf(v[i]);
                Bh[nf][i] = (short)h;
                Bl[nf][i] = (short)f2bf(v[i] - bf2f(h));
            }
        }
        // A fragments loaded transiently per mf (8 regs live, not 64)
        #pragma unroll
        for (int mf = 0; mf < 8; ++mf) {
            size_t aoff = ((size_t)(ks * 4 + g) * DD + (mf * 16 + lc)) * 8;
            bf16x8 Ah = *reinterpret_cast<const bf16x8*>(WA + aoff);
            bf16x8 Al = *reinterpret_cast<const bf16x8*>(WA + 16384 + aoff);
            #pragma unroll
            for (int nf = 0; nf < 2; ++nf) {
                acc[mf][nf] = __builtin_amdgcn_mfma_f32_16x16x32_bf16(Ah, Bh[nf], acc[mf][nf], 0, 0, 0);
                acc[mf][nf] = __builtin_amdgcn_mfma_f32_16x16x32_bf16(Al, Bh[nf], acc[mf][nf], 0, 0, 0);
                acc[mf][nf] = __builtin_amdgcn_mfma_f32_16x16x32_bf16(Ah, Bl[nf], acc[mf][nf], 0, 0, 0);
            }
        }
    }

    // epilogue: per acc reg r, feature f = mf*16 + g*4 + r; edge = ev[nf]
    float partial[2] = {0.f, 0.f};
    #pragma unroll
    for (int mf = 0; mf < 8; ++mf) {
        int f0 = mf * 16 + g * 4;
        float4 attv = *reinterpret_cast<const float4*>(att + f0);
        #pragma unroll
        for (int nf = 0; nf < 2; ++nf) {
            float4 xlv = *reinterpret_cast<const float4*>(xl + (size_t)sn[nf] * DD + f0);
            float4 xrv = *reinterpret_cast<const float4*>(xr + (size_t)dn[nf] * DD + f0);
            float t0 = acc[mf][nf][0] + xlv.x + xrv.x;
            float t1 = acc[mf][nf][1] + xlv.y + xrv.y;
            float t2 = acc[mf][nf][2] + xlv.z + xrv.z;
            float t3 = acc[mf][nf][3] + xlv.w + xrv.w;
            partial[nf] += attv.x * lrelu(t0) + attv.y * lrelu(t1)
                         + attv.z * lrelu(t2) + attv.w * lrelu(t3);
        }
    }
    #pragma unroll
    for (int nf = 0; nf < 2; ++nf) {
        float p = partial[nf];
        p += __shfl_xor(p, 16);
        p += __shfl_xor(p, 32);
        if (lane < 16 && ok[nf]) logits[ev[nf]] = p;
    }
}

// per-destination softmax + aggregation over CSR
__global__ __launch_bounds__(128) void k_node_agg(
    const float* __restrict__ logits, const int* __restrict__ row_ptr,
    const int* __restrict__ eids, const int* __restrict__ srcArr,
    const float* __restrict__ xl, const float* __restrict__ bias,
    float* __restrict__ xout, int N, int E) {
    __shared__ float red[128];
    __shared__ float s_alpha[128];
    __shared__ int s_s[128];
    int n = blockIdx.x;
    int t = threadIdx.x;
    int s = row_ptr[n], e = row_ptr[n + 1];
    float mx = -FLT_MAX;
    for (int p = s + t; p < e; p += 128) mx = fmaxf(mx, logits[eids[p]]);
    red[t] = mx; __syncthreads();
    for (int off = 64; off; off >>= 1) {
        if (t < off) red[t] = fmaxf(red[t], red[t + off]);
        __syncthreads();
    }
    mx = red[0]; __syncthreads();
    float sm = 0.f;
    for (int p = s + t; p < e; p += 128) sm += __expf(logits[eids[p]] - mx);
    red[t] = sm; __syncthreads();
    for (int off = 64; off; off >>= 1) {
        if (t < off) red[t] += red[t + off];
        __syncthreads();
    }
    float inv = 1.0f / red[0];
    float acc = 0.f;
    for (int p0 = s; p0 < e; p0 += 128) {
        int m = min(128, e - p0);
        __syncthreads();
        if (t < m) {
            int eid = eids[p0 + t];
            s_alpha[t] = __expf(logits[eid] - mx) * inv;
            s_s[t] = (eid < E) ? srcArr[eid] : (eid - E);
        }
        __syncthreads();
        for (int q = 0; q < m; ++q)
            acc += s_alpha[q] * xl[(size_t)s_s[q] * DD + t];
    }
    xout[(size_t)n * DD + t] = acc + bias[t];
}

// ---------------- final score + top-k ----------------

__global__ __launch_bounds__(256) void k_scores(const float* __restrict__ X,
                                                const float* __restrict__ Wf,
                                                const float* __restrict__ bf,
                                                float* __restrict__ scores, int N) {
    int gid = blockIdx.x * blockDim.x + threadIdx.x;
    int node = gid >> 6;
    int lane = threadIdx.x & 63;
    if (node >= N) return;
    float2 xv = *reinterpret_cast<const float2*>(&X[(size_t)node * DD + lane * 2]);
    float2 wv = *reinterpret_cast<const float2*>(&Wf[lane * 2]);
    float p = xv.x * wv.x + xv.y * wv.y;
    p += __shfl_xor(p, 32);
    p += __shfl_xor(p, 16);
    p += __shfl_xor(p, 8);
    p += __shfl_xor(p, 4);
    p += __shfl_xor(p, 2);
    p += __shfl_xor(p, 1);
    if (lane == 0) scores[node] = p + bf[0];
}

__device__ __forceinline__ bool tk_better(float a, int ai, float b, int bi) {
    return (a > b) || (a == b && ai < bi);
}

__global__ __launch_bounds__(1024) void k_topk(const float* __restrict__ scores, int N,
                                               float* __restrict__ out) {
    __shared__ float lv[1024 * 10];
    __shared__ int li[1024 * 10];
    int t = threadIdx.x;
    float v[10]; int ix[10];
    #pragma unroll
    for (int j = 0; j < 10; ++j) { v[j] = -FLT_MAX; ix[j] = 0x7fffffff; }
    for (int i = t; i < N; i += 1024) {
        float sv = scores[i];
        if (tk_better(sv, i, v[9], ix[9])) {
            v[9] = sv; ix[9] = i;
            #pragma unroll
            for (int j = 9; j > 0; --j) {
                if (tk_better(v[j], ix[j], v[j - 1], ix[j - 1])) {
                    float tv = v[j]; v[j] = v[j - 1]; v[j - 1] = tv;
                    int ti = ix[j]; ix[j] = ix[j - 1]; ix[j - 1] = ti;
                }
            }
        }
    }
    #pragma unroll
    for (int j = 0; j < 10; ++j) { lv[t * 10 + j] = v[j]; li[t * 10 + j] = ix[j]; }
    __syncthreads();
    for (int sh = 512; sh >= 1; sh >>= 1) {
        if (t < sh) {
            float bv[10]; int bi[10];
            #pragma unroll
            for (int j = 0; j < 10; ++j) { bv[j] = lv[(t + sh) * 10 + j]; bi[j] = li[(t + sh) * 10 + j]; }
            float mv[10]; int mi[10];
            int i1 = 0, i2 = 0;
            #pragma unroll
            for (int k = 0; k < 10; ++k) {
                if (tk_better(v[i1], ix[i1], bv[i2], bi[i2])) { mv[k] = v[i1]; mi[k] = ix[i1]; ++i1; }
                else { mv[k] = bv[i2]; mi[k] = bi[i2]; ++i2; }
            }
            #pragma unroll
            for (int j = 0; j < 10; ++j) {
                v[j] = mv[j]; ix[j] = mi[j];
                lv[t * 10 + j] = v[j]; li[t * 10 + j] = ix[j];
            }
        }
        __syncthreads();
    }
    if (t == 0) {
        #pragma unroll
        for (int j = 0; j < 10; ++j) {
            out[j] = v[j];
            out[10 + j] = (float)ix[j];
        }
    }
}

// ---------------- host launch ----------------

static inline size_t alignup(size_t v) { return (v + 255) & ~(size_t)255; }

extern "C" void kernel_launch(void* const* d_in, const int* in_sizes, int n_in,
                              void* d_out, int out_size, void* d_ws, size_t ws_size,
                              hipStream_t stream) {
    const float* x    = (const float*)d_in[0];
    const int*   ei   = (const int*)d_in[1];
    const float* ea   = (const float*)d_in[2];
    const float* Wl   = (const float*)d_in[3];
    const float* bl   = (const float*)d_in[4];
    const float* Wr   = (const float*)d_in[5];
    const float* br   = (const float*)d_in[6];
    const float* We   = (const float*)d_in[7];
    const float* att  = (const float*)d_in[8];
    const float* bias = (const float*)d_in[9];
    const float* Wf   = (const float*)d_in[10];
    const float* bf   = (const float*)d_in[11];

    int N = in_sizes[0] / DD;
    int E = in_sizes[1] / 2;
    int L = in_sizes[3] / (DD * DD);
    int Etot = E + N;
    const int* src = ei;
    const int* dst = ei + E;

    size_t off = 0;
    char* wsb = (char*)d_ws;
    auto carve = [&](size_t bytes) -> void* { void* p = wsb + off; off += alignup(bytes); return p; };
    unsigned short* WA = (unsigned short*)carve((size_t)L * 32768 * 2);
    int*   cnt       = (int*)carve((size_t)N * 4);
    int*   fill      = (int*)carve((size_t)N * 4);
    int*   row_ptr   = (int*)carve((size_t)(N + 1) * 4);
    int*   eids      = (int*)carve((size_t)Etot * 4);
    float* logits    = (float*)carve((size_t)Etot * 4);
    float* loop_attr = (float*)carve((size_t)N * DD * 4);
    float* xl        = (float*)carve((size_t)N * DD * 4);
    float* xr        = (float*)carve((size_t)N * DD * 4);
    float* xa        = (float*)carve((size_t)N * DD * 4);
    float* xb        = (float*)carve((size_t)N * DD * 4);
    float* scoresBuf = (float*)carve((size_t)N * 4);
    (void)ws_size; (void)n_in; (void)out_size;

    hipMemsetAsync(cnt, 0, (size_t)N * 4, stream);
    hipMemsetAsync(fill, 0, (size_t)N * 4, stream);

    k_prepack<<<(L * DD * DD + 255) / 256, 256, 0, stream>>>(We, WA, L);
    k_hist<<<(E + 255) / 256, 256, 0, stream>>>(dst, E, cnt);
    k_scan<<<1, 1024, 0, stream>>>(cnt, row_ptr, N);
    k_scatter<<<(Etot + 255) / 256, 256, 0, stream>>>(dst, E, N, row_ptr, fill, cnt, eids);
    k_sort_rows<<<(N + 255) / 256, 256, 0, stream>>>(row_ptr, eids, N);
    k_loop_attr<<<N, 128, 0, stream>>>(ea, row_ptr, cnt, eids, loop_attr, N);

    const float* xin = x;
    float* xout = xa;
    int gemmBlocks = (N + 127) / 128;
    int edgeBlocks = (Etot + 127) / 128;
    for (int l = 0; l < L; ++l) {
        k_gemm_nn<<<gemmBlocks, 256, 0, stream>>>(xin, Wl + (size_t)l * DD * DD, bl + (size_t)l * DD, xl, N);
        k_gemm_nn<<<gemmBlocks, 256, 0, stream>>>(xin, Wr + (size_t)l * DD * DD, br + (size_t)l * DD, xr, N);
        k_edge_mfma<<<edgeBlocks, 256, 0, stream>>>(ea, loop_attr, src, dst,
                                                    WA + (size_t)l * 32768, att + (size_t)l * DD,
                                                    xl, xr, logits, E, Etot);
        k_node_agg<<<N, 128, 0, stream>>>(logits, row_ptr, eids, src, xl, bias + (size_t)l * DD, xout, N, E);
        xin = xout;
        xout = (xout == xa) ? xb : xa;
    }
    k_scores<<<(N + 3) / 4, 256, 0, stream>>>(xin, Wf, bf, scoresBuf, N);
    k_topk<<<1, 1024, 0, stream>>>(scoresBuf, N, (float*)d_out);
}